// Round 1
// baseline (5795.133 us; speedup 1.0000x reference)
//
#include <hip/hip_runtime.h>
#include <math.h>

#define NN 20000   // nodes
#define NE 100000  // edges per edge set
#define DD 128     // hidden
#define FF 16      // node features
#define NL 12      // layers
#define NG 64      // graphs

__device__ __forceinline__ float silu_f(float x) { return x / (1.0f + __expf(-x)); }

// ---------------- embedding: h = x @ emb_W + emb_b ----------------
__global__ void embed_kernel(const float* __restrict__ x, const float* __restrict__ W,
                             const float* __restrict__ b, float* __restrict__ h) {
    int gid = blockIdx.x * 256 + threadIdx.x;
    if (gid >= NN * DD) return;
    int n = gid >> 7, c = gid & 127;
    float s = b[c];
    const float* xr = x + n * FF;
#pragma unroll
    for (int k = 0; k < FF; ++k) s += xr[k] * W[k * DD + c];
    h[gid] = s;
}

// ---------------- message MLP (fused 2 GEMMs + 2 LN/SiLU) + scatter-add ----
// tile: 64 edges x 128 cols, 256 threads, each thread 4 rows x 8 cols
__global__ __launch_bounds__(256, 2)
void msg_kernel(const float* __restrict__ h, const float* __restrict__ pos,
                const int* __restrict__ eidx,
                const float* __restrict__ W1, const float* __restrict__ b1,
                const float* __restrict__ g1, const float* __restrict__ be1,
                const float* __restrict__ W2, const float* __restrict__ b2,
                const float* __restrict__ g2, const float* __restrict__ be2,
                float* __restrict__ agg) {
    __shared__ float As[64][33];
    __shared__ float Ws[32][128];
    __shared__ float Mt[64][129];
    __shared__ float dsh[64];
    __shared__ int src_sh[64], dst_sh[64];

    const int tid = threadIdx.x;
    const int tx = tid & 15;        // 0..15
    const int ty = tid >> 4;        // 0..15
    const int r0 = ty * 4;          // 4 rows per thread
    const int cA = tx * 4;          // cols cA..cA+3
    const int cB = 64 + tx * 4;     // cols cB..cB+3
    const int e0 = blockIdx.x * 64;

    if (tid < 64) {
        int e = e0 + tid;
        int s = 0, dn = 0; float dd = 0.f;
        if (e < NE) {
            s  = eidx[e];           // row 0 = src
            dn = eidx[NE + e];      // row 1 = dst
            float dx = pos[dn*3+0] - pos[s*3+0];
            float dy = pos[dn*3+1] - pos[s*3+1];
            float dz = pos[dn*3+2] - pos[s*3+2];
            dd = sqrtf(dx*dx + dy*dy + dz*dz);
        }
        src_sh[tid] = s; dst_sh[tid] = dn; dsh[tid] = dd;
    }
    __syncthreads();

    float acc[4][8];
#pragma unroll
    for (int i = 0; i < 4; ++i)
#pragma unroll
        for (int j = 0; j < 8; ++j) acc[i][j] = 0.f;

    const int la_col = tid & 31, la_r0 = tid >> 5;     // A staging
    const int lw_col = tid & 127, lw_r0 = tid >> 7;    // W staging

    // ---- GEMM1: A[64,256] (h[dst] || h[src]) @ W1[0:256,:] ----
    for (int kc = 0; kc < 8; ++kc) {
        const int kb = kc * 32;
        __syncthreads();
#pragma unroll
        for (int r = 0; r < 64; r += 8) {
            int e = r + la_r0;
            int k = kb + la_col;
            int node = (k < DD) ? dst_sh[e] : src_sh[e];
            As[e][la_col] = h[node * DD + (k & (DD - 1))];
        }
#pragma unroll
        for (int r = 0; r < 32; r += 2)
            Ws[r + lw_r0][lw_col] = W1[(kb + r + lw_r0) * DD + lw_col];
        __syncthreads();
#pragma unroll
        for (int kk = 0; kk < 32; ++kk) {
            float a[4];
#pragma unroll
            for (int i = 0; i < 4; ++i) a[i] = As[r0 + i][kk];
            float4 wA = *(const float4*)&Ws[kk][cA];
            float4 wB = *(const float4*)&Ws[kk][cB];
            float w[8] = {wA.x, wA.y, wA.z, wA.w, wB.x, wB.y, wB.z, wB.w};
#pragma unroll
            for (int i = 0; i < 4; ++i)
#pragma unroll
                for (int j = 0; j < 8; ++j) acc[i][j] += a[i] * w[j];
        }
    }

    // ---- distance column (k=256) + bias, then LN1 + SiLU -> Mt ----
    {
        float4 wA = *(const float4*)&W1[256 * DD + cA];
        float4 wB = *(const float4*)&W1[256 * DD + cB];
        float w[8] = {wA.x, wA.y, wA.z, wA.w, wB.x, wB.y, wB.z, wB.w};
        float4 bA = *(const float4*)&b1[cA];
        float4 bB = *(const float4*)&b1[cB];
        float bb[8] = {bA.x, bA.y, bA.z, bA.w, bB.x, bB.y, bB.z, bB.w};
#pragma unroll
        for (int i = 0; i < 4; ++i) {
            float dd = dsh[r0 + i];
#pragma unroll
            for (int j = 0; j < 8; ++j) acc[i][j] += dd * w[j] + bb[j];
        }
    }
    {
        float4 gA = *(const float4*)&g1[cA];
        float4 gB = *(const float4*)&g1[cB];
        float gg[8] = {gA.x, gA.y, gA.z, gA.w, gB.x, gB.y, gB.z, gB.w};
        float4 eA = *(const float4*)&be1[cA];
        float4 eB = *(const float4*)&be1[cB];
        float ee[8] = {eA.x, eA.y, eA.z, eA.w, eB.x, eB.y, eB.z, eB.w};
#pragma unroll
        for (int i = 0; i < 4; ++i) {
            float s1 = 0.f, s2 = 0.f;
#pragma unroll
            for (int j = 0; j < 8; ++j) { float v = acc[i][j]; s1 += v; s2 += v * v; }
#pragma unroll
            for (int m = 1; m < 16; m <<= 1) { s1 += __shfl_xor(s1, m); s2 += __shfl_xor(s2, m); }
            float mu = s1 * (1.f / 128.f);
            float var = s2 * (1.f / 128.f) - mu * mu;
            float rs = rsqrtf(var + 1e-5f);
#pragma unroll
            for (int j = 0; j < 8; ++j) {
                float v = (acc[i][j] - mu) * rs * gg[j] + ee[j];
                int col = (j < 4) ? (cA + j) : (cB + j - 4);
                Mt[r0 + i][col] = silu_f(v);
            }
        }
    }

    // ---- GEMM2: Mt[64,128] @ W2 ----
#pragma unroll
    for (int i = 0; i < 4; ++i)
#pragma unroll
        for (int j = 0; j < 8; ++j) acc[i][j] = 0.f;
    for (int kc = 0; kc < 4; ++kc) {
        const int kb = kc * 32;
        __syncthreads();
#pragma unroll
        for (int r = 0; r < 32; r += 2)
            Ws[r + lw_r0][lw_col] = W2[(kb + r + lw_r0) * DD + lw_col];
        __syncthreads();
#pragma unroll
        for (int kk = 0; kk < 32; ++kk) {
            float a[4];
#pragma unroll
            for (int i = 0; i < 4; ++i) a[i] = Mt[r0 + i][kb + kk];
            float4 wA = *(const float4*)&Ws[kk][cA];
            float4 wB = *(const float4*)&Ws[kk][cB];
            float w[8] = {wA.x, wA.y, wA.z, wA.w, wB.x, wB.y, wB.z, wB.w};
#pragma unroll
            for (int i = 0; i < 4; ++i)
#pragma unroll
                for (int j = 0; j < 8; ++j) acc[i][j] += a[i] * w[j];
        }
    }

    // ---- bias + LN2 + SiLU + atomic scatter to agg[dst] ----
    {
        float4 bA = *(const float4*)&b2[cA];
        float4 bB = *(const float4*)&b2[cB];
        float bb[8] = {bA.x, bA.y, bA.z, bA.w, bB.x, bB.y, bB.z, bB.w};
        float4 gA = *(const float4*)&g2[cA];
        float4 gB = *(const float4*)&g2[cB];
        float gg[8] = {gA.x, gA.y, gA.z, gA.w, gB.x, gB.y, gB.z, gB.w};
        float4 eA = *(const float4*)&be2[cA];
        float4 eB = *(const float4*)&be2[cB];
        float ee[8] = {eA.x, eA.y, eA.z, eA.w, eB.x, eB.y, eB.z, eB.w};
#pragma unroll
        for (int i = 0; i < 4; ++i) {
            float s1 = 0.f, s2 = 0.f;
#pragma unroll
            for (int j = 0; j < 8; ++j) { float v = acc[i][j] + bb[j]; acc[i][j] = v; s1 += v; s2 += v * v; }
#pragma unroll
            for (int m = 1; m < 16; m <<= 1) { s1 += __shfl_xor(s1, m); s2 += __shfl_xor(s2, m); }
            float mu = s1 * (1.f / 128.f);
            float var = s2 * (1.f / 128.f) - mu * mu;
            float rs = rsqrtf(var + 1e-5f);
            int e = e0 + r0 + i;
            if (e < NE) {
                int dn = dst_sh[r0 + i];
                float* ap = agg + (size_t)dn * DD;
#pragma unroll
                for (int j = 0; j < 8; ++j) {
                    float v = (acc[i][j] - mu) * rs * gg[j] + ee[j];
                    int col = (j < 4) ? (cA + j) : (cB + j - 4);
                    atomicAdd(ap + col, silu_f(v));
                }
            }
        }
    }
}

// ---------------- node update MLP (fused) + residual ----------------
__global__ __launch_bounds__(256, 2)
void upd_kernel(float* __restrict__ h, const float* __restrict__ agg,
                const float* __restrict__ W1, const float* __restrict__ b1,
                const float* __restrict__ g1, const float* __restrict__ be1,
                const float* __restrict__ W2, const float* __restrict__ b2,
                const float* __restrict__ g2, const float* __restrict__ be2) {
    __shared__ float As[64][33];
    __shared__ float Ws[32][128];
    __shared__ float Mt[64][129];

    const int tid = threadIdx.x;
    const int tx = tid & 15;
    const int ty = tid >> 4;
    const int r0 = ty * 4;
    const int cA = tx * 4;
    const int cB = 64 + tx * 4;
    const int n0 = blockIdx.x * 64;

    float acc[4][8];
#pragma unroll
    for (int i = 0; i < 4; ++i)
#pragma unroll
        for (int j = 0; j < 8; ++j) acc[i][j] = 0.f;

    const int la_col = tid & 31, la_r0 = tid >> 5;
    const int lw_col = tid & 127, lw_r0 = tid >> 7;

    // ---- GEMM1: A[64,256] = (h || agg) ----
    for (int kc = 0; kc < 8; ++kc) {
        const int kb = kc * 32;
        __syncthreads();
#pragma unroll
        for (int r = 0; r < 64; r += 8) {
            int rr = r + la_r0;
            int n = n0 + rr;
            int k = kb + la_col;
            float v = 0.f;
            if (n < NN) v = (k < DD) ? h[n * DD + k] : agg[n * DD + (k - DD)];
            As[rr][la_col] = v;
        }
#pragma unroll
        for (int r = 0; r < 32; r += 2)
            Ws[r + lw_r0][lw_col] = W1[(kb + r + lw_r0) * DD + lw_col];
        __syncthreads();
#pragma unroll
        for (int kk = 0; kk < 32; ++kk) {
            float a[4];
#pragma unroll
            for (int i = 0; i < 4; ++i) a[i] = As[r0 + i][kk];
            float4 wA = *(const float4*)&Ws[kk][cA];
            float4 wB = *(const float4*)&Ws[kk][cB];
            float w[8] = {wA.x, wA.y, wA.z, wA.w, wB.x, wB.y, wB.z, wB.w};
#pragma unroll
            for (int i = 0; i < 4; ++i)
#pragma unroll
                for (int j = 0; j < 8; ++j) acc[i][j] += a[i] * w[j];
        }
    }

    // ---- bias + LN1 + SiLU -> Mt ----
    {
        float4 bA = *(const float4*)&b1[cA];
        float4 bB = *(const float4*)&b1[cB];
        float bb[8] = {bA.x, bA.y, bA.z, bA.w, bB.x, bB.y, bB.z, bB.w};
        float4 gA = *(const float4*)&g1[cA];
        float4 gB = *(const float4*)&g1[cB];
        float gg[8] = {gA.x, gA.y, gA.z, gA.w, gB.x, gB.y, gB.z, gB.w};
        float4 eA = *(const float4*)&be1[cA];
        float4 eB = *(const float4*)&be1[cB];
        float ee[8] = {eA.x, eA.y, eA.z, eA.w, eB.x, eB.y, eB.z, eB.w};
#pragma unroll
        for (int i = 0; i < 4; ++i) {
            float s1 = 0.f, s2 = 0.f;
#pragma unroll
            for (int j = 0; j < 8; ++j) { float v = acc[i][j] + bb[j]; acc[i][j] = v; s1 += v; s2 += v * v; }
#pragma unroll
            for (int m = 1; m < 16; m <<= 1) { s1 += __shfl_xor(s1, m); s2 += __shfl_xor(s2, m); }
            float mu = s1 * (1.f / 128.f);
            float var = s2 * (1.f / 128.f) - mu * mu;
            float rs = rsqrtf(var + 1e-5f);
#pragma unroll
            for (int j = 0; j < 8; ++j) {
                float v = (acc[i][j] - mu) * rs * gg[j] + ee[j];
                int col = (j < 4) ? (cA + j) : (cB + j - 4);
                Mt[r0 + i][col] = silu_f(v);
            }
        }
    }

    // ---- GEMM2 ----
#pragma unroll
    for (int i = 0; i < 4; ++i)
#pragma unroll
        for (int j = 0; j < 8; ++j) acc[i][j] = 0.f;
    for (int kc = 0; kc < 4; ++kc) {
        const int kb = kc * 32;
        __syncthreads();
#pragma unroll
        for (int r = 0; r < 32; r += 2)
            Ws[r + lw_r0][lw_col] = W2[(kb + r + lw_r0) * DD + lw_col];
        __syncthreads();
#pragma unroll
        for (int kk = 0; kk < 32; ++kk) {
            float a[4];
#pragma unroll
            for (int i = 0; i < 4; ++i) a[i] = Mt[r0 + i][kb + kk];
            float4 wA = *(const float4*)&Ws[kk][cA];
            float4 wB = *(const float4*)&Ws[kk][cB];
            float w[8] = {wA.x, wA.y, wA.z, wA.w, wB.x, wB.y, wB.z, wB.w};
#pragma unroll
            for (int i = 0; i < 4; ++i)
#pragma unroll
                for (int j = 0; j < 8; ++j) acc[i][j] += a[i] * w[j];
        }
    }

    // ---- bias + LN2 + SiLU + residual h += u ----
    {
        float4 bA = *(const float4*)&b2[cA];
        float4 bB = *(const float4*)&b2[cB];
        float bb[8] = {bA.x, bA.y, bA.z, bA.w, bB.x, bB.y, bB.z, bB.w};
        float4 gA = *(const float4*)&g2[cA];
        float4 gB = *(const float4*)&g2[cB];
        float gg[8] = {gA.x, gA.y, gA.z, gA.w, gB.x, gB.y, gB.z, gB.w};
        float4 eA = *(const float4*)&be2[cA];
        float4 eB = *(const float4*)&be2[cB];
        float ee[8] = {eA.x, eA.y, eA.z, eA.w, eB.x, eB.y, eB.z, eB.w};
#pragma unroll
        for (int i = 0; i < 4; ++i) {
            float s1 = 0.f, s2 = 0.f;
#pragma unroll
            for (int j = 0; j < 8; ++j) { float v = acc[i][j] + bb[j]; acc[i][j] = v; s1 += v; s2 += v * v; }
#pragma unroll
            for (int m = 1; m < 16; m <<= 1) { s1 += __shfl_xor(s1, m); s2 += __shfl_xor(s2, m); }
            float mu = s1 * (1.f / 128.f);
            float var = s2 * (1.f / 128.f) - mu * mu;
            float rs = rsqrtf(var + 1e-5f);
            int n = n0 + r0 + i;
            if (n < NN) {
#pragma unroll
                for (int j = 0; j < 8; ++j) {
                    float v = (acc[i][j] - mu) * rs * gg[j] + ee[j];
                    int col = (j < 4) ? (cA + j) : (cB + j - 4);
                    h[n * DD + col] += silu_f(v);
                }
            }
        }
    }
}

// ---------------- global add pool ----------------
__global__ void pool_kernel(const float* __restrict__ h, const int* __restrict__ batch,
                            float* __restrict__ pooled) {
    int gid = blockIdx.x * 256 + threadIdx.x;
    if (gid >= NN * DD) return;
    int n = gid >> 7, c = gid & 127;
    atomicAdd(&pooled[batch[n] * DD + c], h[gid]);
}

// ---------------- prediction head ----------------
__global__ __launch_bounds__(128)
void pred_kernel(const float* __restrict__ pooled,
                 const float* __restrict__ W1, const float* __restrict__ b1,
                 const float* __restrict__ W2, const float* __restrict__ b2,
                 float* __restrict__ out) {
    __shared__ float prow[128];
    __shared__ float wsum[2];
    int g = blockIdx.x, c = threadIdx.x;
    prow[c] = pooled[g * DD + c];
    __syncthreads();
    float t = b1[c];
#pragma unroll 8
    for (int k = 0; k < DD; ++k) t += prow[k] * W1[k * DD + c];
    t = fmaxf(t, 0.f) * W2[c];
#pragma unroll
    for (int m = 32; m >= 1; m >>= 1) t += __shfl_down(t, m);
    if ((c & 63) == 0) wsum[c >> 6] = t;
    __syncthreads();
    if (c == 0) out[g] = wsum[0] + wsum[1] + b2[0];
}

extern "C" void kernel_launch(void* const* d_in, const int* in_sizes, int n_in,
                              void* d_out, int out_size, void* d_ws, size_t ws_size,
                              hipStream_t stream) {
    const float* x    = (const float*)d_in[0];
    const float* pos  = (const float*)d_in[1];
    const int* eidx[4] = {(const int*)d_in[2], (const int*)d_in[3],
                          (const int*)d_in[4], (const int*)d_in[5]};
    const int* batch  = (const int*)d_in[6];
    const float* emb_W  = (const float*)d_in[7];
    const float* emb_b  = (const float*)d_in[8];
    const float* msg_W1 = (const float*)d_in[9];
    const float* msg_b1 = (const float*)d_in[10];
    const float* msg_g1 = (const float*)d_in[11];
    const float* msg_be1= (const float*)d_in[12];
    const float* msg_W2 = (const float*)d_in[13];
    const float* msg_b2 = (const float*)d_in[14];
    const float* msg_g2 = (const float*)d_in[15];
    const float* msg_be2= (const float*)d_in[16];
    const float* upd_W1 = (const float*)d_in[17];
    const float* upd_b1 = (const float*)d_in[18];
    const float* upd_g1 = (const float*)d_in[19];
    const float* upd_be1= (const float*)d_in[20];
    const float* upd_W2 = (const float*)d_in[21];
    const float* upd_b2 = (const float*)d_in[22];
    const float* upd_g2 = (const float*)d_in[23];
    const float* upd_be2= (const float*)d_in[24];
    const float* pred_W1= (const float*)d_in[25];
    const float* pred_b1= (const float*)d_in[26];
    const float* pred_W2= (const float*)d_in[27];
    const float* pred_b2= (const float*)d_in[28];
    float* out = (float*)d_out;

    float* h      = (float*)d_ws;
    float* agg    = h + (size_t)NN * DD;
    float* pooled = agg + (size_t)NN * DD;

    embed_kernel<<<(NN * DD + 255) / 256, 256, 0, stream>>>(x, emb_W, emb_b, h);

    for (int li = 0; li < NL; ++li) {
        int gi = li & 3;
        hipMemsetAsync(agg, 0, (size_t)NN * DD * sizeof(float), stream);
        msg_kernel<<<(NE + 63) / 64, 256, 0, stream>>>(
            h, pos, eidx[gi],
            msg_W1 + (size_t)li * 257 * DD, msg_b1 + li * DD, msg_g1 + li * DD, msg_be1 + li * DD,
            msg_W2 + (size_t)li * DD * DD,  msg_b2 + li * DD, msg_g2 + li * DD, msg_be2 + li * DD,
            agg);
        upd_kernel<<<(NN + 63) / 64, 256, 0, stream>>>(
            h, agg,
            upd_W1 + (size_t)li * 256 * DD, upd_b1 + li * DD, upd_g1 + li * DD, upd_be1 + li * DD,
            upd_W2 + (size_t)li * DD * DD,  upd_b2 + li * DD, upd_g2 + li * DD, upd_be2 + li * DD);
    }

    hipMemsetAsync(pooled, 0, NG * DD * sizeof(float), stream);
    pool_kernel<<<(NN * DD + 255) / 256, 256, 0, stream>>>(h, batch, pooled);
    pred_kernel<<<NG, 128, 0, stream>>>(pooled, pred_W1, pred_b1, pred_W2, pred_b2, out);
}

// Round 2
// 1197.803 us; speedup vs baseline: 4.8381x; 4.8381x over previous
//
#include <hip/hip_runtime.h>
#include <math.h>

#define NN 20000   // nodes
#define NE 100000  // edges per edge set
#define DD 128     // hidden
#define FF 16      // node features
#define NL 12      // layers
#define NG 64      // graphs

typedef unsigned short u16;
typedef short short8 __attribute__((ext_vector_type(8)));
typedef float f32x4 __attribute__((ext_vector_type(4)));

__device__ __forceinline__ float silu_f(float x) { return x / (1.0f + __expf(-x)); }

// round-to-nearest-even f32 -> bf16
__device__ __forceinline__ u16 f2b(float f) {
    union { float f; unsigned int u; } v; v.f = f;
    unsigned int r = v.u + 0x7fffu + ((v.u >> 16) & 1u);
    return (u16)(r >> 16);
}

// ---- weight prep: convert fp32 [L][Ksrc][128] -> bf16 transposed [L][128][Kdst] ----
__global__ void wprep_kernel(const float* __restrict__ src, u16* __restrict__ dst,
                             int Ksrc, int Kdst) {
    int gid = blockIdx.x * 256 + threadIdx.x;
    int total = NL * 128 * Kdst;
    if (gid >= total) return;
    int k = gid % Kdst;
    int c = (gid / Kdst) & 127;
    int l = gid / (Kdst * 128);
    dst[gid] = f2b(src[((size_t)l * Ksrc + k) * 128 + c]);
}

// ---- embedding: h = x @ emb_W + emb_b (also writes bf16 shadow) ----
__global__ void embed_kernel(const float* __restrict__ x, const float* __restrict__ W,
                             const float* __restrict__ b, float* __restrict__ h,
                             u16* __restrict__ hb) {
    int gid = blockIdx.x * 256 + threadIdx.x;
    if (gid >= NN * DD) return;
    int n = gid >> 7, c = gid & 127;
    float s = b[c];
    const float* xr = x + n * FF;
#pragma unroll
    for (int k = 0; k < FF; ++k) s += xr[k] * W[k * DD + c];
    h[gid] = s;
    hb[gid] = f2b(s);
}

// =======================================================================
// message MLP: MFMA 16x16x32 bf16, 64 edges x 128 cols per block, 4 waves
// =======================================================================
__global__ __launch_bounds__(256, 4)
void msg_kernel(const u16* __restrict__ hb, const float* __restrict__ pos,
                const int* __restrict__ eidx,
                const u16* __restrict__ W1T,   // [128][256] bf16 (k<256)
                const float* __restrict__ W1f, // fp32 [257][128] (for k=256 row)
                const float* __restrict__ b1, const float* __restrict__ g1,
                const float* __restrict__ be1,
                const u16* __restrict__ W2T,   // [128][128] bf16
                const float* __restrict__ b2, const float* __restrict__ g2,
                const float* __restrict__ be2,
                float* __restrict__ agg) {
    __shared__ __align__(16) u16 As[64 * 40];   // pad stride 40 -> 2-way banks (free)
    __shared__ __align__(16) u16 Ws[128 * 40];
    __shared__ __align__(16) u16 Mt[64 * 136];
    __shared__ float dsh[64];
    __shared__ int dst_sh[64], src_sh[64];

    const int tid = threadIdx.x;
    const int lane = tid & 63;
    const int w = tid >> 6;
    const int r0 = w * 16;
    const int arow = lane & 15;
    const int kg = lane >> 4;
    const int e0 = blockIdx.x * 64;

    if (tid < 64) {
        int e = e0 + tid;
        int s = 0, dn = 0; float dd = 0.f;
        if (e < NE) {
            s = eidx[e];
            dn = eidx[NE + e];
            float dx = pos[dn * 3 + 0] - pos[s * 3 + 0];
            float dy = pos[dn * 3 + 1] - pos[s * 3 + 1];
            float dz = pos[dn * 3 + 2] - pos[s * 3 + 2];
            dd = sqrtf(dx * dx + dy * dy + dz * dz);
        }
        src_sh[tid] = s; dst_sh[tid] = dn; dsh[tid] = dd;
    }
    __syncthreads();

    f32x4 acc[8];
#pragma unroll
    for (int t = 0; t < 8; ++t) acc[t] = (f32x4)0.f;

    const int s_row = tid >> 2, s_k8 = (tid & 3) * 8;
    const int w_col = tid >> 1, w_k16 = (tid & 1) * 16;

    // ---- GEMM1: [64,256] (h[dst]||h[src]) @ W1 ----
    for (int kc = 0; kc < 8; ++kc) {
        const int kb = kc * 32;
        {
            int k = kb + s_k8;
            int node = (k < DD) ? dst_sh[s_row] : src_sh[s_row];
            *(short8*)&As[s_row * 40 + s_k8] =
                *(const short8*)&hb[(size_t)node * DD + (k & (DD - 1))];
            const u16* wsrc = &W1T[(size_t)w_col * 256 + kb + w_k16];
            *(short8*)&Ws[w_col * 40 + w_k16]     = *(const short8*)&wsrc[0];
            *(short8*)&Ws[w_col * 40 + w_k16 + 8] = *(const short8*)&wsrc[8];
        }
        __syncthreads();
        short8 a = *(const short8*)&As[(r0 + arow) * 40 + kg * 8];
#pragma unroll
        for (int t = 0; t < 8; ++t) {
            short8 b = *(const short8*)&Ws[(t * 16 + arow) * 40 + kg * 8];
            acc[t] = __builtin_amdgcn_mfma_f32_16x16x32_bf16(a, b, acc[t], 0, 0, 0);
        }
        __syncthreads();
    }

    // ---- distance col (k=256) + bias + LN1 + SiLU -> Mt (bf16) ----
    {
        float gg[8], ee[8];
#pragma unroll
        for (int t = 0; t < 8; ++t) {
            int col = t * 16 + arow;
            float wd = W1f[256 * DD + col];
            float bb = b1[col];
            gg[t] = g1[col]; ee[t] = be1[col];
#pragma unroll
            for (int r = 0; r < 4; ++r)
                acc[t][r] += dsh[r0 + kg * 4 + r] * wd + bb;
        }
#pragma unroll
        for (int r = 0; r < 4; ++r) {
            float s1 = 0.f, s2 = 0.f;
#pragma unroll
            for (int t = 0; t < 8; ++t) { float v = acc[t][r]; s1 += v; s2 += v * v; }
#pragma unroll
            for (int m = 1; m < 16; m <<= 1) { s1 += __shfl_xor(s1, m); s2 += __shfl_xor(s2, m); }
            float mu = s1 * (1.f / 128.f);
            float var = s2 * (1.f / 128.f) - mu * mu;
            float rs = rsqrtf(var + 1e-5f);
            int row = r0 + kg * 4 + r;
#pragma unroll
            for (int t = 0; t < 8; ++t) {
                float v = (acc[t][r] - mu) * rs * gg[t] + ee[t];
                Mt[row * 136 + t * 16 + arow] = f2b(silu_f(v));
            }
        }
    }
    __syncthreads();

    // ---- GEMM2: M[64,128] @ W2 ----
#pragma unroll
    for (int t = 0; t < 8; ++t) acc[t] = (f32x4)0.f;
    for (int kc = 0; kc < 4; ++kc) {
        const int kb = kc * 32;
        {
            const u16* wsrc = &W2T[(size_t)w_col * 128 + kb + w_k16];
            *(short8*)&Ws[w_col * 40 + w_k16]     = *(const short8*)&wsrc[0];
            *(short8*)&Ws[w_col * 40 + w_k16 + 8] = *(const short8*)&wsrc[8];
        }
        __syncthreads();
        short8 a = *(const short8*)&Mt[(r0 + arow) * 136 + kb + kg * 8];
#pragma unroll
        for (int t = 0; t < 8; ++t) {
            short8 b = *(const short8*)&Ws[(t * 16 + arow) * 40 + kg * 8];
            acc[t] = __builtin_amdgcn_mfma_f32_16x16x32_bf16(a, b, acc[t], 0, 0, 0);
        }
        __syncthreads();
    }

    // ---- bias + LN2 + SiLU + atomic scatter to agg[dst] ----
    {
        float gg[8], ee[8], bb[8];
#pragma unroll
        for (int t = 0; t < 8; ++t) {
            int col = t * 16 + arow;
            bb[t] = b2[col]; gg[t] = g2[col]; ee[t] = be2[col];
        }
#pragma unroll
        for (int r = 0; r < 4; ++r) {
            int row = r0 + kg * 4 + r;
            float s1 = 0.f, s2 = 0.f;
#pragma unroll
            for (int t = 0; t < 8; ++t) {
                float v = acc[t][r] + bb[t]; acc[t][r] = v; s1 += v; s2 += v * v;
            }
#pragma unroll
            for (int m = 1; m < 16; m <<= 1) { s1 += __shfl_xor(s1, m); s2 += __shfl_xor(s2, m); }
            float mu = s1 * (1.f / 128.f);
            float var = s2 * (1.f / 128.f) - mu * mu;
            float rs = rsqrtf(var + 1e-5f);
            int e = e0 + row;
            if (e < NE) {
                float* ap = agg + (size_t)dst_sh[row] * DD;
#pragma unroll
                for (int t = 0; t < 8; ++t) {
                    float v = (acc[t][r] - mu) * rs * gg[t] + ee[t];
                    atomicAdd(ap + t * 16 + arow, silu_f(v));
                }
            }
        }
    }
}

// =======================================================================
// node update MLP: MFMA, 64 nodes x 128 cols per block + residual
// =======================================================================
__global__ __launch_bounds__(256, 4)
void upd_kernel(float* __restrict__ h, u16* __restrict__ hb,
                const float* __restrict__ agg,
                const u16* __restrict__ W1T,
                const float* __restrict__ b1, const float* __restrict__ g1,
                const float* __restrict__ be1,
                const u16* __restrict__ W2T,
                const float* __restrict__ b2, const float* __restrict__ g2,
                const float* __restrict__ be2) {
    __shared__ __align__(16) u16 As[64 * 40];
    __shared__ __align__(16) u16 Ws[128 * 40];
    __shared__ __align__(16) u16 Mt[64 * 136];

    const int tid = threadIdx.x;
    const int lane = tid & 63;
    const int w = tid >> 6;
    const int r0 = w * 16;
    const int arow = lane & 15;
    const int kg = lane >> 4;
    const int n0 = blockIdx.x * 64;

    f32x4 acc[8];
#pragma unroll
    for (int t = 0; t < 8; ++t) acc[t] = (f32x4)0.f;

    const int s_row = tid >> 2, s_k8 = (tid & 3) * 8;
    const int w_col = tid >> 1, w_k16 = (tid & 1) * 16;

    // ---- GEMM1: [64,256] (h || agg) @ W1 ----
    for (int kc = 0; kc < 8; ++kc) {
        const int kb = kc * 32;
        {
            int k = kb + s_k8;
            int n = n0 + s_row;
            int nn = (n < NN) ? n : 0;
            if (k < DD) {
                *(short8*)&As[s_row * 40 + s_k8] =
                    *(const short8*)&hb[(size_t)nn * DD + k];
            } else {
                const float* ap = &agg[(size_t)nn * DD + (k - DD)];
                float4 f0 = *(const float4*)ap;
                float4 f1 = *(const float4*)(ap + 4);
                u16 tmp[8];
                tmp[0] = f2b(f0.x); tmp[1] = f2b(f0.y); tmp[2] = f2b(f0.z); tmp[3] = f2b(f0.w);
                tmp[4] = f2b(f1.x); tmp[5] = f2b(f1.y); tmp[6] = f2b(f1.z); tmp[7] = f2b(f1.w);
                *(short8*)&As[s_row * 40 + s_k8] = *(const short8*)tmp;
            }
            const u16* wsrc = &W1T[(size_t)w_col * 256 + kb + w_k16];
            *(short8*)&Ws[w_col * 40 + w_k16]     = *(const short8*)&wsrc[0];
            *(short8*)&Ws[w_col * 40 + w_k16 + 8] = *(const short8*)&wsrc[8];
        }
        __syncthreads();
        short8 a = *(const short8*)&As[(r0 + arow) * 40 + kg * 8];
#pragma unroll
        for (int t = 0; t < 8; ++t) {
            short8 b = *(const short8*)&Ws[(t * 16 + arow) * 40 + kg * 8];
            acc[t] = __builtin_amdgcn_mfma_f32_16x16x32_bf16(a, b, acc[t], 0, 0, 0);
        }
        __syncthreads();
    }

    // ---- bias + LN1 + SiLU -> Mt ----
    {
        float gg[8], ee[8], bb[8];
#pragma unroll
        for (int t = 0; t < 8; ++t) {
            int col = t * 16 + arow;
            bb[t] = b1[col]; gg[t] = g1[col]; ee[t] = be1[col];
        }
#pragma unroll
        for (int r = 0; r < 4; ++r) {
            float s1 = 0.f, s2 = 0.f;
#pragma unroll
            for (int t = 0; t < 8; ++t) {
                float v = acc[t][r] + bb[t]; acc[t][r] = v; s1 += v; s2 += v * v;
            }
#pragma unroll
            for (int m = 1; m < 16; m <<= 1) { s1 += __shfl_xor(s1, m); s2 += __shfl_xor(s2, m); }
            float mu = s1 * (1.f / 128.f);
            float var = s2 * (1.f / 128.f) - mu * mu;
            float rs = rsqrtf(var + 1e-5f);
            int row = r0 + kg * 4 + r;
#pragma unroll
            for (int t = 0; t < 8; ++t) {
                float v = (acc[t][r] - mu) * rs * gg[t] + ee[t];
                Mt[row * 136 + t * 16 + arow] = f2b(silu_f(v));
            }
        }
    }
    __syncthreads();

    // ---- GEMM2 ----
#pragma unroll
    for (int t = 0; t < 8; ++t) acc[t] = (f32x4)0.f;
    for (int kc = 0; kc < 4; ++kc) {
        const int kb = kc * 32;
        {
            const u16* wsrc = &W2T[(size_t)w_col * 128 + kb + w_k16];
            *(short8*)&Ws[w_col * 40 + w_k16]     = *(const short8*)&wsrc[0];
            *(short8*)&Ws[w_col * 40 + w_k16 + 8] = *(const short8*)&wsrc[8];
        }
        __syncthreads();
        short8 a = *(const short8*)&Mt[(r0 + arow) * 136 + kb + kg * 8];
#pragma unroll
        for (int t = 0; t < 8; ++t) {
            short8 b = *(const short8*)&Ws[(t * 16 + arow) * 40 + kg * 8];
            acc[t] = __builtin_amdgcn_mfma_f32_16x16x32_bf16(a, b, acc[t], 0, 0, 0);
        }
        __syncthreads();
    }

    // ---- bias + LN2 + SiLU + residual (h fp32 + hb bf16) ----
    {
        float gg[8], ee[8], bb[8];
#pragma unroll
        for (int t = 0; t < 8; ++t) {
            int col = t * 16 + arow;
            bb[t] = b2[col]; gg[t] = g2[col]; ee[t] = be2[col];
        }
#pragma unroll
        for (int r = 0; r < 4; ++r) {
            int row = r0 + kg * 4 + r;
            float s1 = 0.f, s2 = 0.f;
#pragma unroll
            for (int t = 0; t < 8; ++t) {
                float v = acc[t][r] + bb[t]; acc[t][r] = v; s1 += v; s2 += v * v;
            }
#pragma unroll
            for (int m = 1; m < 16; m <<= 1) { s1 += __shfl_xor(s1, m); s2 += __shfl_xor(s2, m); }
            float mu = s1 * (1.f / 128.f);
            float var = s2 * (1.f / 128.f) - mu * mu;
            float rs = rsqrtf(var + 1e-5f);
            int n = n0 + row;
            if (n < NN) {
                float* hp = &h[(size_t)n * DD];
                u16* hbp = &hb[(size_t)n * DD];
#pragma unroll
                for (int t = 0; t < 8; ++t) {
                    int col = t * 16 + arow;
                    float v = (acc[t][r] - mu) * rs * gg[t] + ee[t];
                    float nh = hp[col] + silu_f(v);
                    hp[col] = nh;
                    hbp[col] = f2b(nh);
                }
            }
        }
    }
}

// ---------------- global add pool ----------------
__global__ void pool_kernel(const float* __restrict__ h, const int* __restrict__ batch,
                            float* __restrict__ pooled) {
    int gid = blockIdx.x * 256 + threadIdx.x;
    if (gid >= NN * DD) return;
    int n = gid >> 7, c = gid & 127;
    atomicAdd(&pooled[batch[n] * DD + c], h[gid]);
}

// ---------------- prediction head ----------------
__global__ __launch_bounds__(128)
void pred_kernel(const float* __restrict__ pooled,
                 const float* __restrict__ W1, const float* __restrict__ b1,
                 const float* __restrict__ W2, const float* __restrict__ b2,
                 float* __restrict__ out) {
    __shared__ float prow[128];
    __shared__ float wsum[2];
    int g = blockIdx.x, c = threadIdx.x;
    prow[c] = pooled[g * DD + c];
    __syncthreads();
    float t = b1[c];
#pragma unroll 8
    for (int k = 0; k < DD; ++k) t += prow[k] * W1[k * DD + c];
    t = fmaxf(t, 0.f) * W2[c];
#pragma unroll
    for (int m = 32; m >= 1; m >>= 1) t += __shfl_down(t, m);
    if ((c & 63) == 0) wsum[c >> 6] = t;
    __syncthreads();
    if (c == 0) out[g] = wsum[0] + wsum[1] + b2[0];
}

extern "C" void kernel_launch(void* const* d_in, const int* in_sizes, int n_in,
                              void* d_out, int out_size, void* d_ws, size_t ws_size,
                              hipStream_t stream) {
    const float* x    = (const float*)d_in[0];
    const float* pos  = (const float*)d_in[1];
    const int* eidx[4] = {(const int*)d_in[2], (const int*)d_in[3],
                          (const int*)d_in[4], (const int*)d_in[5]};
    const int* batch  = (const int*)d_in[6];
    const float* emb_W  = (const float*)d_in[7];
    const float* emb_b  = (const float*)d_in[8];
    const float* msg_W1 = (const float*)d_in[9];
    const float* msg_b1 = (const float*)d_in[10];
    const float* msg_g1 = (const float*)d_in[11];
    const float* msg_be1= (const float*)d_in[12];
    const float* msg_W2 = (const float*)d_in[13];
    const float* msg_b2 = (const float*)d_in[14];
    const float* msg_g2 = (const float*)d_in[15];
    const float* msg_be2= (const float*)d_in[16];
    const float* upd_W1 = (const float*)d_in[17];
    const float* upd_b1 = (const float*)d_in[18];
    const float* upd_g1 = (const float*)d_in[19];
    const float* upd_be1= (const float*)d_in[20];
    const float* upd_W2 = (const float*)d_in[21];
    const float* upd_b2 = (const float*)d_in[22];
    const float* upd_g2 = (const float*)d_in[23];
    const float* upd_be2= (const float*)d_in[24];
    const float* pred_W1= (const float*)d_in[25];
    const float* pred_b1= (const float*)d_in[26];
    const float* pred_W2= (const float*)d_in[27];
    const float* pred_b2= (const float*)d_in[28];
    float* out = (float*)d_out;

    float* h      = (float*)d_ws;
    float* agg    = h + (size_t)NN * DD;
    float* pooled = agg + (size_t)NN * DD;
    u16* hb       = (u16*)(pooled + NG * DD);
    u16* msgW1T   = hb + (size_t)NN * DD;
    u16* msgW2T   = msgW1T + (size_t)NL * 128 * 256;
    u16* updW1T   = msgW2T + (size_t)NL * 128 * 128;
    u16* updW2T   = updW1T + (size_t)NL * 128 * 256;

    int t1 = NL * 128 * 256, t2 = NL * 128 * 128;
    wprep_kernel<<<(t1 + 255) / 256, 256, 0, stream>>>(msg_W1, msgW1T, 257, 256);
    wprep_kernel<<<(t2 + 255) / 256, 256, 0, stream>>>(msg_W2, msgW2T, 128, 128);
    wprep_kernel<<<(t1 + 255) / 256, 256, 0, stream>>>(upd_W1, updW1T, 256, 256);
    wprep_kernel<<<(t2 + 255) / 256, 256, 0, stream>>>(upd_W2, updW2T, 128, 128);

    embed_kernel<<<(NN * DD + 255) / 256, 256, 0, stream>>>(x, emb_W, emb_b, h, hb);

    for (int li = 0; li < NL; ++li) {
        int gi = li & 3;
        hipMemsetAsync(agg, 0, (size_t)NN * DD * sizeof(float), stream);
        msg_kernel<<<(NE + 63) / 64, 256, 0, stream>>>(
            hb, pos, eidx[gi],
            msgW1T + (size_t)li * 128 * 256,
            msg_W1 + (size_t)li * 257 * DD,
            msg_b1 + li * DD, msg_g1 + li * DD, msg_be1 + li * DD,
            msgW2T + (size_t)li * 128 * 128,
            msg_b2 + li * DD, msg_g2 + li * DD, msg_be2 + li * DD,
            agg);
        upd_kernel<<<(NN + 63) / 64, 256, 0, stream>>>(
            h, hb, agg,
            updW1T + (size_t)li * 128 * 256,
            upd_b1 + li * DD, upd_g1 + li * DD, upd_be1 + li * DD,
            updW2T + (size_t)li * 128 * 128,
            upd_b2 + li * DD, upd_g2 + li * DD, upd_be2 + li * DD);
    }

    hipMemsetAsync(pooled, 0, NG * DD * sizeof(float), stream);
    pool_kernel<<<(NN * DD + 255) / 256, 256, 0, stream>>>(h, batch, pooled);
    pred_kernel<<<NG, 128, 0, stream>>>(pooled, pred_W1, pred_b1, pred_W2, pred_b2, out);
}